// Round 1
// baseline (100.519 us; speedup 1.0000x reference)
//
#include <hip/hip_runtime.h>

// VectorQuantizer on MI355X (gfx950).
// out[0 .. 8388607] = z + (codebook[argmin] - z)   (f32)
// out[8388608]      = 1.25 * mean((z_q - z)^2)     (f32)
//
// argmin over squared distance d_k = ||E_k||^2 - 2 z.E_k  (||z||^2 dropped: row-constant).
// Scaled: E' = 1024*E  ->  minimize  ||E'||^2/2048 - z.E'  ==  maximize  s - cadj.
// s computed via 3-pass bf16-split MFMA (hh + lh + hl), error ~1e-9 of typical gaps.

typedef __attribute__((ext_vector_type(8))) short bf16x8;
typedef __attribute__((ext_vector_type(4))) float f32x4;

#define N_TOKENS 131072
#define NUM_CODES 1024
#define DIM 64

__device__ __forceinline__ short f32_bf16(float f) {
  unsigned u = __builtin_bit_cast(unsigned, f);
  unsigned r = u + 0x7FFFu + ((u >> 16) & 1u);   // round-to-nearest-even
  return (short)(r >> 16);
}
__device__ __forceinline__ float bf16_f32(short h) {
  unsigned u = ((unsigned)(unsigned short)h) << 16;
  return __builtin_bit_cast(float, u);
}

// ---------------- kernel 1: codebook prep (bf16 hi/lo + cadj) + zero accum ----
__global__ __launch_bounds__(256) void vq_prep(
    const float* __restrict__ cb, unsigned short* __restrict__ ch,
    unsigned short* __restrict__ cl, float* __restrict__ cadj,
    double* __restrict__ accum) {
  const int lane = threadIdx.x & 63;
  const int wv = threadIdx.x >> 6;
  const int code = blockIdx.x * 4 + wv;      // 256 blocks * 4 waves = 1024 codes
  const float e = cb[code * DIM + lane] * 1024.0f;   // exact pow2 scale
  const short h = f32_bf16(e);
  const float hv = bf16_f32(h);
  const short l = f32_bf16(e - hv);
  ch[code * DIM + lane] = (unsigned short)h;
  cl[code * DIM + lane] = (unsigned short)l;
  float sq = e * e;
  #pragma unroll
  for (int w = 32; w >= 1; w >>= 1) sq += __shfl_xor(sq, w, 64);
  if (lane == 0) cadj[code] = sq * (1.0f / 2048.0f);
  if (blockIdx.x == 0 && threadIdx.x == 0) *accum = 0.0;
}

// ---------------- kernel 2: fused score + argmin ------------------------------
// block = 256 thr = 4 waves; wave owns 64 rows x all 1024 codes (32-col tiles).
__global__ __launch_bounds__(256, 2) void vq_argmin(
    const float* __restrict__ z, const unsigned short* __restrict__ ch,
    const unsigned short* __restrict__ cl, const float* __restrict__ cadj,
    int* __restrict__ idxout) {
  const int lane = threadIdx.x & 63;
  const int wv = threadIdx.x >> 6;
  const int g = lane >> 4;          // k-group / C row-group
  const int c15 = lane & 15;        // A row / B col / C col within 16-tile
  const int rowbase = blockIdx.x * 256 + wv * 64;

  // A fragments (z rows), bf16 hi/lo, held in registers for the whole kernel.
  // 16x16x32 layout: A row = c15, k = kk*32 + g*8 + j  (k-permutation cancels
  // between A and B as long as both sides use the same mapping).
  bf16x8 ah[4][2], al[4][2];
  #pragma unroll
  for (int m = 0; m < 4; ++m) {
    const float* zp = z + (size_t)(rowbase + m * 16 + c15) * DIM;
    #pragma unroll
    for (int kk = 0; kk < 2; ++kk) {
      const int k0 = kk * 32 + g * 8;
      #pragma unroll
      for (int j = 0; j < 8; ++j) {
        const float v = zp[k0 + j];
        const short h = f32_bf16(v);
        ah[m][kk][j] = h;
        al[m][kk][j] = f32_bf16(v - bf16_f32(h));
      }
    }
  }

  float best[4][4];
  int bidx[4][4];
  #pragma unroll
  for (int m = 0; m < 4; ++m)
    #pragma unroll
    for (int r = 0; r < 4; ++r) { best[m][r] = -3.0e38f; bidx[m][r] = 0; }

  auto loadB = [&](int ct, bf16x8 (&bh)[2][2], bf16x8 (&bl)[2][2],
                   float (&ca)[2]) {
    #pragma unroll
    for (int n = 0; n < 2; ++n) {
      const int code = ct * 32 + n * 16 + c15;
      #pragma unroll
      for (int kk = 0; kk < 2; ++kk) {
        const int off = code * DIM + kk * 32 + g * 8;
        bh[n][kk] = *(const bf16x8*)(ch + off);
        bl[n][kk] = *(const bf16x8*)(cl + off);
      }
      ca[n] = cadj[code];
    }
  };

  auto process = [&](int ct, bf16x8 (&bh)[2][2], bf16x8 (&bl)[2][2],
                     float (&ca)[2]) {
    f32x4 acc[2][4];
    #pragma unroll
    for (int n = 0; n < 2; ++n)
      #pragma unroll
      for (int m = 0; m < 4; ++m)
        acc[n][m] = (f32x4){0.f, 0.f, 0.f, 0.f};
    #pragma unroll
    for (int kk = 0; kk < 2; ++kk)
      #pragma unroll
      for (int n = 0; n < 2; ++n)
        #pragma unroll
        for (int m = 0; m < 4; ++m) {
          acc[n][m] = __builtin_amdgcn_mfma_f32_16x16x32_bf16(
              ah[m][kk], bh[n][kk], acc[n][m], 0, 0, 0);
          acc[n][m] = __builtin_amdgcn_mfma_f32_16x16x32_bf16(
              al[m][kk], bh[n][kk], acc[n][m], 0, 0, 0);
          acc[n][m] = __builtin_amdgcn_mfma_f32_16x16x32_bf16(
              ah[m][kk], bl[n][kk], acc[n][m], 0, 0, 0);
        }
    // running argmax of (s - cadj); strictly-greater keeps earliest col (np tie rule)
    #pragma unroll
    for (int n = 0; n < 2; ++n) {
      const int col = ct * 32 + n * 16 + c15;
      #pragma unroll
      for (int m = 0; m < 4; ++m)
        #pragma unroll
        for (int r = 0; r < 4; ++r) {
          const float v = acc[n][m][r] - ca[n];
          if (v > best[m][r]) { best[m][r] = v; bidx[m][r] = col; }
        }
    }
  };

  // ping-pong software pipeline over the 32 column tiles
  bf16x8 bh0[2][2], bl0[2][2], bh1[2][2], bl1[2][2];
  float ca0[2], ca1[2];
  loadB(0, bh0, bl0, ca0);
  #pragma unroll 1
  for (int ct2 = 0; ct2 < 16; ++ct2) {
    const int ct = ct2 * 2;
    loadB(ct + 1, bh1, bl1, ca1);
    process(ct, bh0, bl0, ca0);
    loadB((ct + 2) & 31, bh0, bl0, ca0);   // last wraps to 0 (unused, valid mem)
    process(ct + 1, bh1, bl1, ca1);
  }

  // reduce across the 16 lanes (c15) of each row-group; prefer smaller idx on tie
  #pragma unroll
  for (int m = 0; m < 4; ++m)
    #pragma unroll
    for (int r = 0; r < 4; ++r) {
      float bv = best[m][r];
      int bi = bidx[m][r];
      #pragma unroll
      for (int w = 1; w < 16; w <<= 1) {
        const float ov = __shfl_xor(bv, w, 64);
        const int oi = __shfl_xor(bi, w, 64);
        if (ov > bv || (ov == bv && oi < bi)) { bv = ov; bi = oi; }
      }
      if (c15 == 0) idxout[rowbase + m * 16 + g * 4 + r] = bi;
    }
}

// ---------------- kernel 3: gather z_q, write out, accumulate loss ------------
__global__ __launch_bounds__(256) void vq_gather_loss(
    const float* __restrict__ z, const float* __restrict__ cb,
    const int* __restrict__ idxs, float* __restrict__ out,
    double* __restrict__ accum) {
  const int lane = threadIdx.x & 63;
  const int wv = threadIdx.x >> 6;
  const int g = lane >> 4, s = lane & 15;
  const int gw = blockIdx.x * 4 + wv;
  const int nw = gridDim.x * 4;
  const f32x4* z4 = (const f32x4*)z;
  const f32x4* cb4 = (const f32x4*)cb;
  f32x4* out4 = (f32x4*)out;

  float psum = 0.0f;
  for (int rb = gw * 4; rb < N_TOKENS; rb += nw * 4) {
    const int row = rb + g;
    const int idx = idxs[row];
    const f32x4 q = cb4[idx * 16 + s];
    const f32x4 zv = z4[(size_t)row * 16 + s];
    f32x4 t, o;
    #pragma unroll
    for (int j = 0; j < 4; ++j) {
      t[j] = q[j] - zv[j];     // (z_q - z), matches reference rounding
      o[j] = zv[j] + t[j];     // z + stop_grad(z_q - z)
    }
    out4[(size_t)row * 16 + s] = o;
    psum += t[0]*t[0] + t[1]*t[1] + t[2]*t[2] + t[3]*t[3];
  }
  #pragma unroll
  for (int w = 32; w >= 1; w >>= 1) psum += __shfl_xor(psum, w, 64);
  __shared__ double wsum[4];
  if (lane == 0) wsum[wv] = (double)psum;
  __syncthreads();
  if (threadIdx.x == 0)
    atomicAdd(accum, wsum[0] + wsum[1] + wsum[2] + wsum[3]);
}

// ---------------- kernel 4: finalize loss scalar ------------------------------
__global__ void vq_finalize(const double* __restrict__ accum,
                            float* __restrict__ out_loss) {
  out_loss[0] = (float)(1.25 * (*accum) / (double)(N_TOKENS * (size_t)DIM));
}

extern "C" void kernel_launch(void* const* d_in, const int* in_sizes, int n_in,
                              void* d_out, int out_size, void* d_ws, size_t ws_size,
                              hipStream_t stream) {
  const float* z = (const float*)d_in[0];
  const float* cb = (const float*)d_in[1];
  float* out = (float*)d_out;
  char* ws = (char*)d_ws;

  // workspace layout (790536 bytes total)
  unsigned short* ch = (unsigned short*)(ws);            // 128 KB
  unsigned short* cl = (unsigned short*)(ws + 131072);   // 128 KB
  float* cadj = (float*)(ws + 262144);                   // 4 KB
  int* idxs = (int*)(ws + 266240);                       // 512 KB
  double* accum = (double*)(ws + 790528);                // 8 B

  vq_prep<<<256, 256, 0, stream>>>(cb, ch, cl, cadj, accum);
  vq_argmin<<<512, 256, 0, stream>>>(z, ch, cl, cadj, idxs);
  vq_gather_loss<<<512, 256, 0, stream>>>(z, cb, idxs, out, accum);
  vq_finalize<<<1, 1, 0, stream>>>(accum, out + (size_t)N_TOKENS * DIM);
}

// Round 2
// 64.835 us; speedup vs baseline: 1.5504x; 1.5504x over previous
//
#include <hip/hip_runtime.h>

// VectorQuantizer on MI355X (gfx950) — v2.
// out[0 .. 8388607] = codebook[argmin_k ||z - E_k||^2]   (f32; == z + (z_q - z) to ~1e-6)
// out[8388608]      = 1.25 * mean((z_q - z)^2)           (f32)
//
// Scoring: maximize  s - ca  where s = z . (1024 E_k) (single-pass bf16 MFMA),
// ca = ||1024 E_k||^2 / 2048.  Key-packed argmax: key = bits(s - ca + 128)
// truncated to 0xFFFFFC00 | (1023 - col); u32 max gives argmax with
// earliest-column tie-break.  Loss fused: ||q - z||^2_row = ||z||^2 + (ca - s*)/512.

typedef __attribute__((ext_vector_type(8))) short bf16x8;
typedef __attribute__((ext_vector_type(4))) float f32x4;

#define N_TOKENS 131072
#define NUM_CODES 1024
#define DIM 64

__device__ __forceinline__ short f32_bf16(float f) {
  unsigned u = __builtin_bit_cast(unsigned, f);
  unsigned r = u + 0x7FFFu + ((u >> 16) & 1u);   // round-to-nearest-even
  return (short)(r >> 16);
}

// ---------------- kernel 1: codebook prep (bf16 + ca2 = 128 - ||E'||^2/2048) --
__global__ __launch_bounds__(256) void vq_prep(
    const float* __restrict__ cb, unsigned short* __restrict__ ch,
    float* __restrict__ ca2, double* __restrict__ accum) {
  const int lane = threadIdx.x & 63;
  const int wv = threadIdx.x >> 6;
  const int code = blockIdx.x * 4 + wv;      // 256 blocks * 4 waves = 1024 codes
  const float e = cb[code * DIM + lane] * 1024.0f;   // exact pow2 scale
  ch[code * DIM + lane] = (unsigned short)f32_bf16(e);
  float sq = e * e;
  #pragma unroll
  for (int w = 32; w >= 1; w >>= 1) sq += __shfl_xor(sq, w, 64);
  if (lane == 0) ca2[code] = 128.0f - sq * (1.0f / 2048.0f);
  if (blockIdx.x == 0 && threadIdx.x == 0) *accum = 0.0;
}

// ---------------- kernel 2: fused score + argmin + loss -----------------------
// block = 256 thr = 4 waves; wave owns 64 rows x all 1024 codes (32-col tiles).
__global__ __launch_bounds__(256, 2) void vq_argmin(
    const float* __restrict__ z, const unsigned short* __restrict__ ch,
    const float* __restrict__ ca2, int* __restrict__ idxout,
    double* __restrict__ accum) {
  const int lane = threadIdx.x & 63;
  const int wv = threadIdx.x >> 6;
  const int g = lane >> 4;          // k-group / C row-group
  const int c15 = lane & 15;        // A row / B col / C col within 16-tile
  const int rowbase = blockIdx.x * 256 + wv * 64;

  // A fragments (z rows) in bf16, held in registers; also accumulate sum(z^2).
  // Each (row,dim) of this wave's 64x64 z block is read by exactly one lane.
  bf16x8 ah[4][2];
  float zsq = 0.0f;
  #pragma unroll
  for (int m = 0; m < 4; ++m) {
    const float* zp = z + (size_t)(rowbase + m * 16 + c15) * DIM;
    #pragma unroll
    for (int kk = 0; kk < 2; ++kk) {
      const int k0 = kk * 32 + g * 8;
      #pragma unroll
      for (int j = 0; j < 8; ++j) {
        const float v = zp[k0 + j];
        ah[m][kk][j] = f32_bf16(v);
        zsq += v * v;
      }
    }
  }

  unsigned best[4][4];
  #pragma unroll
  for (int m = 0; m < 4; ++m)
    #pragma unroll
    for (int r = 0; r < 4; ++r) best[m][r] = 0u;

  auto loadB = [&](int ct, bf16x8 (&bh)[2][2], float (&ca)[2]) {
    #pragma unroll
    for (int n = 0; n < 2; ++n) {
      const int code = ct * 32 + n * 16 + c15;
      #pragma unroll
      for (int kk = 0; kk < 2; ++kk)
        bh[n][kk] = *(const bf16x8*)(ch + code * DIM + kk * 32 + g * 8);
      ca[n] = ca2[code];
    }
  };

  auto process = [&](int ct, bf16x8 (&bh)[2][2], float (&ca)[2]) {
    f32x4 acc[2][4];
    #pragma unroll
    for (int n = 0; n < 2; ++n)
      #pragma unroll
      for (int m = 0; m < 4; ++m)
        acc[n][m] = (f32x4){0.f, 0.f, 0.f, 0.f};
    #pragma unroll
    for (int kk = 0; kk < 2; ++kk)
      #pragma unroll
      for (int n = 0; n < 2; ++n)
        #pragma unroll
        for (int m = 0; m < 4; ++m)
          acc[n][m] = __builtin_amdgcn_mfma_f32_16x16x32_bf16(
              ah[m][kk], bh[n][kk], acc[n][m], 0, 0, 0);
    #pragma unroll
    for (int n = 0; n < 2; ++n) {
      const unsigned colcode = 1023u - (unsigned)(ct * 32 + n * 16 + c15);
      #pragma unroll
      for (int m = 0; m < 4; ++m)
        #pragma unroll
        for (int r = 0; r < 4; ++r) {
          const float v = acc[n][m][r] + ca[n];           // s - cadj + 128 > 0
          const unsigned key =
              (__builtin_bit_cast(unsigned, v) & 0xFFFFFC00u) | colcode;
          best[m][r] = key > best[m][r] ? key : best[m][r];   // v_max_u32
        }
    }
  };

  // ping-pong software pipeline over the 32 column tiles
  bf16x8 bh0[2][2], bh1[2][2];
  float ca0[2], ca1[2];
  loadB(0, bh0, ca0);
  #pragma unroll 1
  for (int ct2 = 0; ct2 < 16; ++ct2) {
    const int ct = ct2 * 2;
    loadB(ct + 1, bh1, ca1);
    process(ct, bh0, ca0);
    loadB((ct + 2) & 31, bh0, ca0);   // last wraps to 0 (unused, valid mem)
    process(ct + 1, bh1, ca1);
  }

  // per-(m,r) max over the 16 c15 lanes; key max = score max + earliest-col tie
  float lossx = 0.0f;
  #pragma unroll
  for (int m = 0; m < 4; ++m)
    #pragma unroll
    for (int r = 0; r < 4; ++r) {
      unsigned bk = best[m][r];
      #pragma unroll
      for (int w = 1; w < 16; w <<= 1) {
        const unsigned ob = __shfl_xor((int)bk, w, 64);
        bk = ob > bk ? ob : bk;
      }
      if (c15 == 0) {
        idxout[rowbase + m * 16 + g * 4 + r] = 1023 - (int)(bk & 1023u);
        // (ca - s*) = 128 - v*;  v* from truncated key bits (bias ~0.016 -> ~3e-7 in loss)
        lossx += 128.0f - __builtin_bit_cast(float, bk & 0xFFFFFC00u);
      }
    }

  // per-row ||q - z||^2 summed:  sum(z^2) + sum(ca - s*)/512
  float psum = zsq + lossx * (1.0f / 512.0f);
  #pragma unroll
  for (int w = 32; w >= 1; w >>= 1) psum += __shfl_xor(psum, w, 64);
  __shared__ double wsum[4];
  if (lane == 0) wsum[wv] = (double)psum;
  __syncthreads();
  if (threadIdx.x == 0)
    atomicAdd(accum, wsum[0] + wsum[1] + wsum[2] + wsum[3]);
}

// ---------------- kernel 3: gather z_q -> out (write-only 32 MB) --------------
__global__ __launch_bounds__(256) void vq_gather(
    const float* __restrict__ cb, const int* __restrict__ idxs,
    float* __restrict__ out) {
  const int lane = threadIdx.x & 63;
  const int wv = threadIdx.x >> 6;
  const int g = lane >> 4, s = lane & 15;
  const int gw = blockIdx.x * 4 + wv;
  const int nw = gridDim.x * 4;
  const f32x4* cb4 = (const f32x4*)cb;
  f32x4* out4 = (f32x4*)out;
  for (int rb = gw * 4; rb < N_TOKENS; rb += nw * 4) {
    const int row = rb + g;
    const int idx = idxs[row];
    out4[(size_t)row * 16 + s] = cb4[idx * 16 + s];
  }
}

// ---------------- kernel 4: finalize loss scalar ------------------------------
__global__ void vq_finalize(const double* __restrict__ accum,
                            float* __restrict__ out_loss) {
  out_loss[0] = (float)(1.25 * (*accum) / (double)(N_TOKENS * (size_t)DIM));
}

extern "C" void kernel_launch(void* const* d_in, const int* in_sizes, int n_in,
                              void* d_out, int out_size, void* d_ws, size_t ws_size,
                              hipStream_t stream) {
  const float* z = (const float*)d_in[0];
  const float* cb = (const float*)d_in[1];
  float* out = (float*)d_out;
  char* ws = (char*)d_ws;

  // workspace layout (659464 bytes used)
  unsigned short* ch = (unsigned short*)(ws);          // 128 KB bf16 codebook*1024
  float* ca2 = (float*)(ws + 131072);                  // 4 KB   128 - ||E'||^2/2048
  int* idxs = (int*)(ws + 135168);                     // 512 KB argmin indices
  double* accum = (double*)(ws + 659456);              // 8 B    loss accumulator

  vq_prep<<<256, 256, 0, stream>>>(cb, ch, ca2, accum);
  vq_argmin<<<512, 256, 0, stream>>>(z, ch, ca2, idxs, accum);
  vq_gather<<<512, 256, 0, stream>>>(cb, idxs, out);
  vq_finalize<<<1, 1, 0, stream>>>(accum, out + (size_t)N_TOKENS * DIM);
}

// Round 3
// 43.345 us; speedup vs baseline: 2.3190x; 1.4958x over previous
//
#include <hip/hip_runtime.h>

// VectorQuantizer on MI355X (gfx950) — v3.
// out[0 .. 8388607] = codebook[argmin_k ||z - E_k||^2]   (f32)
// out[8388608]      = 1.25 * mean((z_q - z)^2)           (f32)
//
// Score: maximize  s + ca  where s = z.(1024 E_k) via single-pass bf16 MFMA and
// ca = 128 - ||1024 E_k||^2/2048 (folded into the MFMA C-init).  Key-packed
// argmax: key = (bits(s+ca) & 0xFFFFFC00) | (1023-col); u32 max = argmax with
// earliest-col tie-break.  Loss fused: ||q-z||^2_row = ||z||^2 + (128 - v*)/512.
// B staged in LDS (double-buffered 64-code stages, global_load_lds w=16,
// XOR-swizzled via pre-swizzled global source) and shared by 4 waves/block.

typedef __attribute__((ext_vector_type(8))) short bf16x8;
typedef __attribute__((ext_vector_type(4))) float f32x4;

#define N_TOKENS 131072
#define DIM 64

__device__ __forceinline__ short f32_bf16(float f) {
  unsigned u = __builtin_bit_cast(unsigned, f);
  unsigned r = u + 0x7FFFu + ((u >> 16) & 1u);   // round-to-nearest-even
  return (short)(r >> 16);
}

// ---------------- kernel 1: codebook prep -------------------------------------
__global__ __launch_bounds__(256) void vq_prep(
    const float* __restrict__ cb, unsigned short* __restrict__ ch,
    float* __restrict__ ca2, double* __restrict__ accum) {
  const int lane = threadIdx.x & 63;
  const int wv = threadIdx.x >> 6;
  const int code = blockIdx.x * 4 + wv;      // 256 blocks * 4 waves = 1024 codes
  const float e = cb[code * DIM + lane] * 1024.0f;   // exact pow2 scale
  ch[code * DIM + lane] = (unsigned short)f32_bf16(e);
  float sq = e * e;
  #pragma unroll
  for (int w = 32; w >= 1; w >>= 1) sq += __shfl_xor(sq, w, 64);
  if (lane == 0) ca2[code] = 128.0f - sq * (1.0f / 2048.0f);
  if (blockIdx.x == 0 && threadIdx.x == 0) *accum = 0.0;
}

// ---------------- kernel 2: fused score + argmin + gather + loss --------------
// block = 256 (4 waves), wave owns 32 rows; block stages B tiles in LDS.
__global__ __launch_bounds__(256, 4) void vq_argmin(
    const float* __restrict__ z, const unsigned short* __restrict__ ch,
    const float* __restrict__ ca2, const float* __restrict__ cb,
    float* __restrict__ out, double* __restrict__ accum) {
  __shared__ unsigned short Bs[2][4096];   // 2 x 8 KB: 64 codes x 64 dims bf16
  __shared__ double wsum[4];
  const int tid = threadIdx.x;
  const int lane = tid & 63;
  const int wv = tid >> 6;
  const int g = lane >> 4;          // k-chunk group / C row-group
  const int c15 = lane & 15;        // A row / B col / C col within 16-tile
  const int rowbase = blockIdx.x * 128 + wv * 32;
  const int sw = c15 & 7;

  // Pre-swizzled per-lane GLOBAL source offsets (shorts) for staging:
  // LDS chunk (code, c) must hold global chunk (code, c ^ (code&7)); the LDS
  // destination of global_load_lds is linear (base + lane*16), so the
  // permutation is applied to the source address.
  int soff[2];
  #pragma unroll
  for (int q = 0; q < 2; ++q) {
    const int Lq = q * 256 + tid;          // linear 16B chunk id, 0..511
    const int code = Lq >> 3, c = Lq & 7;
    soff[q] = code * DIM + ((c ^ (code & 7)) << 3);
  }

  auto stage = [&](int s, int buf) {
    #pragma unroll
    for (int q = 0; q < 2; ++q) {
      const unsigned short* src = ch + s * 4096 + soff[q];
      __builtin_amdgcn_global_load_lds(
          (const __attribute__((address_space(1))) unsigned int*)src,
          (__attribute__((address_space(3))) unsigned int*)
              &Bs[buf][q * 2048 + wv * 512],
          16, 0, 0);
    }
  };

  // prologue: ca for stage 0, issue stage 0, load A-frags (hides stage latency)
  float cas[4];
  #pragma unroll
  for (int i = 0; i < 4; ++i) cas[i] = ca2[i * 16 + c15];
  stage(0, 0);

  bf16x8 ah[2][2];
  float zsq = 0.0f;
  #pragma unroll
  for (int m = 0; m < 2; ++m)
    #pragma unroll
    for (int kk = 0; kk < 2; ++kk) {
      const f32x4* zp4 = (const f32x4*)(
          z + (size_t)(rowbase + m * 16 + c15) * DIM + kk * 32 + g * 8);
      const f32x4 v0 = zp4[0], v1 = zp4[1];
      #pragma unroll
      for (int j = 0; j < 4; ++j) {
        ah[m][kk][j]     = f32_bf16(v0[j]);
        ah[m][kk][j + 4] = f32_bf16(v1[j]);
        zsq += v0[j] * v0[j] + v1[j] * v1[j];
      }
    }

  unsigned best[2][4];
  #pragma unroll
  for (int m = 0; m < 2; ++m)
    #pragma unroll
    for (int r = 0; r < 4; ++r) best[m][r] = 0u;

  // swizzled per-lane ds_read base offsets (bytes) for kk = 0,1
  const int vb[2] = { c15 * 128 + ((g ^ sw) << 4),
                      c15 * 128 + (((4 + g) ^ sw) << 4) };
  const char* bsp = (const char*)Bs;
  const unsigned kmask = 0xFFFFFC00u;

  __syncthreads();   // stage 0 landed

  #pragma unroll 1
  for (int s = 0; s < 16; ++s) {
    const int sb = s & 1;
    if (s < 15) stage(s + 1, sb ^ 1);          // issue next stage first (T3)
    float nxt[4];
    {
      const int sn = (s < 15) ? s + 1 : 0;     // wrap: valid mem, unused
      #pragma unroll
      for (int i = 0; i < 4; ++i) nxt[i] = ca2[sn * 64 + i * 16 + c15];
    }
    #pragma unroll
    for (int h = 0; h < 2; ++h) {              // two 32-code tiles per stage
      const int t = s * 2 + h;
      bf16x8 bf[2][2];
      #pragma unroll
      for (int n = 0; n < 2; ++n)
        #pragma unroll
        for (int kk = 0; kk < 2; ++kk)
          bf[n][kk] = *(const bf16x8*)(
              bsp + sb * 8192 + h * 4096 + n * 2048 + vb[kk]);
      f32x4 acc[2][2];                         // C-init = ca (saves the add)
      #pragma unroll
      for (int n = 0; n < 2; ++n) {
        const float c = cas[h * 2 + n];
        #pragma unroll
        for (int m = 0; m < 2; ++m) acc[n][m] = (f32x4){c, c, c, c};
      }
      #pragma unroll
      for (int kk = 0; kk < 2; ++kk)
        #pragma unroll
        for (int n = 0; n < 2; ++n)
          #pragma unroll
          for (int m = 0; m < 2; ++m)
            acc[n][m] = __builtin_amdgcn_mfma_f32_16x16x32_bf16(
                ah[m][kk], bf[n][kk], acc[n][m], 0, 0, 0);
      #pragma unroll
      for (int n = 0; n < 2; ++n) {
        const unsigned colcode = 1023u - (unsigned)(t * 32 + n * 16 + c15);
        #pragma unroll
        for (int m = 0; m < 2; ++m)
          #pragma unroll
          for (int r = 0; r < 4; ++r) {
            const unsigned key =
                (__builtin_bit_cast(unsigned, acc[n][m][r]) & kmask) | colcode;
            best[m][r] = key > best[m][r] ? key : best[m][r];   // v_max_u32
          }
      }
    }
    __syncthreads();   // drains stage(s+1) loads; protects buf reuse
    #pragma unroll
    for (int i = 0; i < 4; ++i) cas[i] = nxt[i];
  }

  // epilogue: butterfly max over the 16 c15 lanes (all lanes get the winner),
  // gather codebook row -> out, accumulate loss.
  float lossx = 0.0f;
  const f32x4* cb4 = (const f32x4*)cb;
  f32x4* out4 = (f32x4*)out;
  #pragma unroll
  for (int m = 0; m < 2; ++m)
    #pragma unroll
    for (int r = 0; r < 4; ++r) {
      unsigned bk = best[m][r];
      #pragma unroll
      for (int w = 1; w < 16; w <<= 1) {
        const unsigned ob = (unsigned)__shfl_xor((int)bk, w, 64);
        bk = ob > bk ? ob : bk;
      }
      const int row = rowbase + m * 16 + g * 4 + r;
      const int bi = 1023 - (int)(bk & 1023u);
      out4[(size_t)row * 16 + c15] = cb4[bi * 16 + c15];
      if (c15 == 0) lossx += 128.0f - __builtin_bit_cast(float, bk & kmask);
    }

  float psum = zsq + lossx * (1.0f / 512.0f);
  #pragma unroll
  for (int w = 32; w >= 1; w >>= 1) psum += __shfl_xor(psum, w, 64);
  if (lane == 0) wsum[wv] = (double)psum;
  __syncthreads();
  if (tid == 0) atomicAdd(accum, wsum[0] + wsum[1] + wsum[2] + wsum[3]);
}

// ---------------- kernel 3: finalize loss scalar ------------------------------
__global__ void vq_finalize(const double* __restrict__ accum,
                            float* __restrict__ out_loss) {
  out_loss[0] = (float)(1.25 * (*accum) / (double)(N_TOKENS * (size_t)DIM));
}

extern "C" void kernel_launch(void* const* d_in, const int* in_sizes, int n_in,
                              void* d_out, int out_size, void* d_ws, size_t ws_size,
                              hipStream_t stream) {
  const float* z = (const float*)d_in[0];
  const float* cb = (const float*)d_in[1];
  float* out = (float*)d_out;
  char* ws = (char*)d_ws;

  // workspace layout (135176 bytes used)
  unsigned short* ch = (unsigned short*)(ws);        // 128 KB bf16 codebook*1024
  float* ca2 = (float*)(ws + 131072);                // 4 KB   128 - ||E'||^2/2048
  double* accum = (double*)(ws + 135168);            // 8 B    loss accumulator

  vq_prep<<<256, 256, 0, stream>>>(cb, ch, ca2, accum);
  vq_argmin<<<1024, 256, 0, stream>>>(z, ch, ca2, cb, out, accum);
  vq_finalize<<<1, 1, 0, stream>>>(accum, out + (size_t)N_TOKENS * DIM);
}